// Round 3
// baseline (277.058 us; speedup 1.0000x reference)
//
#include <hip/hip_runtime.h>
#include <hip/hip_bf16.h>

typedef __bf16 bf16_t;
typedef __bf16 bf16x8 __attribute__((ext_vector_type(8)));
typedef float  floatx4 __attribute__((ext_vector_type(4)));

#define BQ 16
#define NTOK 2048
#define DIM 256
#define HD 64

// ---------------- Kernel 0: W -> W^T bf16 ----------------
__global__ __launch_bounds__(256) void k_prep(const float* __restrict__ Wq,
                                              const float* __restrict__ Wk,
                                              const float* __restrict__ Wv,
                                              bf16_t* __restrict__ wt) {
    int o = blockIdx.x * 256 + threadIdx.x;
    int w = o >> 14;
    int r = o & 16383;
    int h = r >> 8;
    int d = r & 255;
    const float* W = (w == 0) ? Wq : ((w == 1) ? Wk : Wv);
    wt[o] = (bf16_t)W[d * 64 + h];
}

// ---------------- Kernel 1: QKV projection (32 tokens/block, 1024 blocks) ----------------
#define XS 264
#define VS 40
__global__ __launch_bounds__(256) void k_qkv(const float* __restrict__ x,
                                             const bf16_t* __restrict__ wt,
                                             const float* __restrict__ bq,
                                             const float* __restrict__ bk,
                                             const float* __restrict__ bv,
                                             bf16_t* __restrict__ qb,
                                             bf16_t* __restrict__ kb,
                                             bf16_t* __restrict__ vt) {
    __shared__ bf16_t x_ls[32 * XS];
    __shared__ bf16_t vt_ls[64 * VS];

    int b  = blockIdx.x >> 6;
    int t0 = (blockIdx.x & 63) << 5;   // 32 tokens per block
    int t  = threadIdx.x;
    int lane = t & 63;
    int w    = t >> 6;
    int m_   = lane & 15;
    int q4   = lane >> 4;

    // stage x (fp32 -> bf16): 32 rows x 64 float4 chunks = 2048
    for (int tau = t; tau < 2048; tau += 256) {
        int row = tau >> 6, ch = tau & 63;
        float4 v = ((const float4*)x)[(size_t)(b * NTOK + t0 + row) * 64 + ch];
        bf16_t tmp[4] = {(bf16_t)v.x, (bf16_t)v.y, (bf16_t)v.z, (bf16_t)v.w};
        *(uint2*)(&x_ls[row * XS + ch * 4]) = *(uint2*)tmp;
    }
    __syncthreads();

    for (int wi = 0; wi < 3; ++wi) {
        const bf16_t* wtw = wt + wi * 16384;
        floatx4 acc[2];
        #pragma unroll
        for (int mt = 0; mt < 2; ++mt) acc[mt] = floatx4{0.f, 0.f, 0.f, 0.f};

        #pragma unroll
        for (int ks = 0; ks < 8; ++ks) {
            bf16x8 bfrag = *(const bf16x8*)(wtw + (16 * w + m_) * 256 + ks * 32 + q4 * 8);
            #pragma unroll
            for (int mt = 0; mt < 2; ++mt) {
                bf16x8 afrag = *(const bf16x8*)(&x_ls[(16 * mt + m_) * XS + ks * 32 + q4 * 8]);
                acc[mt] = __builtin_amdgcn_mfma_f32_16x16x32_bf16(afrag, bfrag, acc[mt], 0, 0, 0);
            }
        }
        const float* bias_p = (wi == 0) ? bq : ((wi == 1) ? bk : bv);
        float bias = bias_p[16 * w + m_];
        float scale = (wi == 0) ? 0.125f : 1.0f;   // fold H^-0.5 into q (exact pow2)

        if (wi < 2) {
            bf16_t* dst = (wi == 0) ? qb : kb;
            #pragma unroll
            for (int mt = 0; mt < 2; ++mt)
                #pragma unroll
                for (int r = 0; r < 4; ++r) {
                    int tok = t0 + 16 * mt + 4 * q4 + r;
                    dst[(size_t)(b * NTOK + tok) * 64 + 16 * w + m_] = (bf16_t)((acc[mt][r] + bias) * scale);
                }
        } else {
            #pragma unroll
            for (int mt = 0; mt < 2; ++mt)
                #pragma unroll
                for (int r = 0; r < 4; ++r)
                    vt_ls[(16 * w + m_) * VS + 16 * mt + 4 * q4 + r] = (bf16_t)(acc[mt][r] + bias);
            __syncthreads();
            if (t < 256) {
                int h = t >> 2, ch = t & 3;
                uint4 val = *(const uint4*)(&vt_ls[h * VS + ch * 8]);
                *(uint4*)(vt + (size_t)(b * 64 + h) * NTOK + t0 + ch * 8) = val;
            }
        }
    }
}

// ---------------- Kernel 2: fused attention ----------------
// frame: 32 rows (r0-1 .. r0+30, interior 30) x 48 cols (c0-1 .. c0+46, interior 46)
#define SA 52     // A_ls fp32 stride
#define SP 72     // bf16 LDS stride
#define RI 30     // interior rows per block
#define NITER 45  // col iterations (46 interior cols each)
#define GRIDX 69  // ceil(2048/30)
__global__ __launch_bounds__(256) void k_attn(const bf16_t* __restrict__ qb,
                                              const bf16_t* __restrict__ kb,
                                              const bf16_t* __restrict__ vt,
                                              const float* __restrict__ conv_w,
                                              const float* __restrict__ conv_b,
                                              float* __restrict__ out) {
    __shared__ bf16_t q_ls[32 * SP];   // 4608 B
    __shared__ bf16_t k_ls[48 * SP];   // 6912 B
    __shared__ bf16_t v_ls[64 * SP];   // 9216 B  [h][k], k=global_col-c0; k>=46 zero
    __shared__ float  A_ls[32 * SA];   // 6656 B  cols 48..51 zero pad
    __shared__ bf16_t p_ls[32 * SP];   // 4608 B  [i][k]; rows 0,31 & k>=46 zero
    __shared__ float  rs_ls[32];       // 128 B          => total 32128 B -> 5 blk/CU

    int b  = blockIdx.y;
    int r0 = blockIdx.x * RI;
    int t = threadIdx.x, lane = t & 63, w = t >> 6;
    int m_ = lane & 15, q4 = lane >> 4;

    const uint* vt32 = (const uint*)vt + (size_t)b * 64 * 1024;

    int vh[6], vc[6];
    #pragma unroll
    for (int j = 0; j < 6; ++j) { int tau = t + 256 * j; vh[j] = tau / 23; vc[j] = tau % 23; }

    float cw[9];
    #pragma unroll
    for (int i = 0; i < 9; ++i) cw[i] = conv_w[i];
    float cb = conv_b[0];

    uint4 kreg[2];
    uint  vreg[6];
    auto prefetch = [&](int c0) {
        {
            int row = t >> 3, ch = t & 7;
            int g = c0 - 1 + row;
            uint4 val = make_uint4(0u, 0u, 0u, 0u);
            if (g >= 0 && g < NTOK)
                val = *(const uint4*)(kb + (size_t)(b * NTOK + g) * 64 + ch * 8);
            kreg[0] = val;
        }
        if (t < 128) {
            int row = (t + 256) >> 3, ch = t & 7;
            int g = c0 - 1 + row;
            uint4 val = make_uint4(0u, 0u, 0u, 0u);
            if (g >= 0 && g < NTOK)
                val = *(const uint4*)(kb + (size_t)(b * NTOK + g) * 64 + ch * 8);
            kreg[1] = val;
        }
        #pragma unroll
        for (int j = 0; j < 6; ++j) {
            if (t + 256 * j < 1472) {
                int n = c0 + 2 * vc[j];
                uint val = 0u;
                if (n < NTOK) val = vt32[vh[j] * 1024 + (n >> 1)];
                vreg[j] = val;
            }
        }
    };

    prefetch(0);

    // one-time zero inits
    for (int u = t; u < 1152; u += 256) ((uint*)p_ls)[u] = 0u;            // whole p_ls (32*72*2/4)
    for (int u = t; u < 1152; u += 256) {                                  // v_ls K-pad cols 46..63
        int h = u / 18, c = 46 + u % 18;
        v_ls[h * SP + c] = (bf16_t)0.f;
    }
    if (t < 128) A_ls[(t >> 2) * SA + 48 + (t & 3)] = 0.f;                 // A_ls col pad rows 0..31
    // stage q: 32 rows x 8 x 16B = 256 chunks, one per thread
    {
        int row = t >> 3, ch = t & 7;
        int g = r0 - 1 + row;
        uint4 val = make_uint4(0u, 0u, 0u, 0u);
        if (g >= 0 && g < NTOK)
            val = *(const uint4*)(qb + (size_t)(b * NTOK + g) * 64 + ch * 8);
        *(uint4*)(&q_ls[row * SP + ch * 8]) = val;
    }

    floatx4 accO[2];
    #pragma unroll
    for (int ti = 0; ti < 2; ++ti) accO[ti] = floatx4{0.f, 0.f, 0.f, 0.f};
    float rs[2] = {0.f, 0.f};

    for (int it = 0; it < NITER; ++it) {
        // ---- regs -> LDS (k_ls, v_ls) ----
        {
            int row = t >> 3, ch = t & 7;
            *(uint4*)(&k_ls[row * SP + ch * 8]) = kreg[0];
            if (t < 128) {
                int row1 = (t + 256) >> 3;
                *(uint4*)(&k_ls[row1 * SP + ch * 8]) = kreg[1];
            }
            #pragma unroll
            for (int j = 0; j < 6; ++j)
                if (t + 256 * j < 1472)
                    *(uint*)(&v_ls[vh[j] * SP + 2 * vc[j]]) = vreg[j];
        }
        __syncthreads();

        // ---- QK^T: 2x3 tiles, K=64 (scale pre-folded into q) ----
        for (int T = w; T < 6; T += 4) {
            int ti = T / 3, tj = T % 3;
            floatx4 a = floatx4{0.f, 0.f, 0.f, 0.f};
            #pragma unroll
            for (int ks = 0; ks < 2; ++ks) {
                bf16x8 af = *(const bf16x8*)(&q_ls[(16 * ti + m_) * SP + ks * 32 + q4 * 8]);
                bf16x8 bf = *(const bf16x8*)(&k_ls[(16 * tj + m_) * SP + ks * 32 + q4 * 8]);
                a = __builtin_amdgcn_mfma_f32_16x16x32_bf16(af, bf, a, 0, 0, 0);
            }
            #pragma unroll
            for (int r = 0; r < 4; ++r)
                A_ls[(16 * ti + 4 * q4 + r) * SA + 16 * tj + m_] = a[r];
        }
        __syncthreads();

        // issue next iter's global loads; latency overlaps conv below
        if (it + 1 < NITER) prefetch((it + 1) * RI * 0 + (it + 1) * 46);

        // ---- conv + sigmoid + relu + expm1 (30x46 interior, 1x4 quads) ----
        #pragma unroll
        for (int round = 0; round < 2; ++round) {
            int idx = t + (round << 8);
            if (idx < 360) {
                int i = idx / 12 + 1;            // row 1..30
                int g = idx - (i - 1) * 12;      // quad col group 0..11
                const float* base = &A_ls[(i - 1) * SA + 4 * g];
                float a0[6], a1[6], a2[6];
                *(float4*)(a0) = *(const float4*)(base);
                *(float2*)(a0 + 4) = *(const float2*)(base + 4);
                *(float4*)(a1) = *(const float4*)(base + SA);
                *(float2*)(a1 + 4) = *(const float2*)(base + SA + 4);
                *(float4*)(a2) = *(const float4*)(base + 2 * SA);
                *(float2*)(a2 + 4) = *(const float2*)(base + 2 * SA + 4);
                float esum = 0.f;
                bf16_t quad[4];
                #pragma unroll
                for (int x = 0; x < 4; ++x) {
                    float conv = cb
                        + cw[0] * a0[x] + cw[1] * a0[x + 1] + cw[2] * a0[x + 2]
                        + cw[3] * a1[x] + cw[4] * a1[x + 1] + cw[5] * a1[x + 2]
                        + cw[6] * a2[x] + cw[7] * a2[x + 1] + cw[8] * a2[x + 2];
                    float sig = __builtin_amdgcn_rcpf(1.f + __expf(-conv));
                    float s = fmaxf(a1[x + 1] - sig, 0.f);
                    float ev = __expf(s) - 1.f;
                    if (4 * g + x > 45) ev = 0.f;     // frame col > 46 (rim / pad)
                    quad[x] = (bf16_t)ev;
                    esum += ev;
                }
                rs[round] += esum;
                *(uint2*)(&p_ls[i * SP + 4 * g]) = *(uint2*)quad;
            }
        }
        __syncthreads();

        // ---- PV: O[32x64] += P @ V ----
        #pragma unroll
        for (int ks = 0; ks < 2; ++ks) {
            bf16x8 bf = *(const bf16x8*)(&v_ls[(16 * w + m_) * SP + ks * 32 + q4 * 8]);
            #pragma unroll
            for (int ti = 0; ti < 2; ++ti) {
                bf16x8 af = *(const bf16x8*)(&p_ls[(16 * ti + m_) * SP + ks * 32 + q4 * 8]);
                accO[ti] = __builtin_amdgcn_mfma_f32_16x16x32_bf16(af, bf, accO[ti], 0, 0, 0);
            }
        }
        __syncthreads();
    }

    // ---- epilogue: rowsum reduction (A_ls reused), divide, store ----
    float* sc = A_ls;
    sc[t * 2 + 0] = rs[0];
    sc[t * 2 + 1] = rs[1];
    __syncthreads();
    if (t < RI) {
        float s = 0.f;
        #pragma unroll
        for (int j = 0; j < 12; ++j) {
            int idx = 12 * t + j;
            s += sc[(idx & 255) * 2 + (idx >> 8)];
        }
        rs_ls[t + 1] = s + 1e-5f;
    }
    __syncthreads();

    #pragma unroll
    for (int ti = 0; ti < 2; ++ti) {
        #pragma unroll
        for (int r = 0; r < 4; ++r) {
            int i = 16 * ti + 4 * q4 + r;
            int grow = r0 + i - 1;
            if (i >= 1 && i < 31 && grow < NTOK)
                out[(size_t)(b * NTOK + grow) * 64 + 16 * w + m_] = accO[ti][r] / rs_ls[i];
        }
    }
}

extern "C" void kernel_launch(void* const* d_in, const int* in_sizes, int n_in,
                              void* d_out, int out_size, void* d_ws, size_t ws_size,
                              hipStream_t stream) {
    const float* x  = (const float*)d_in[0];
    const float* Wq = (const float*)d_in[1];
    const float* bq = (const float*)d_in[2];
    const float* Wk = (const float*)d_in[3];
    const float* bk = (const float*)d_in[4];
    const float* Wv = (const float*)d_in[5];
    const float* bv = (const float*)d_in[6];
    const float* cw = (const float*)d_in[7];
    const float* cb = (const float*)d_in[8];
    float* out = (float*)d_out;

    char* ws = (char*)d_ws;
    bf16_t* wt = (bf16_t*)ws;
    bf16_t* qb = (bf16_t*)(ws + 98304);
    bf16_t* kb = (bf16_t*)(ws + 98304 + 4194304);
    bf16_t* vt = (bf16_t*)(ws + 98304 + 8388608);

    k_prep<<<dim3(192), dim3(256), 0, stream>>>(Wq, Wk, Wv, wt);
    k_qkv<<<dim3(1024), dim3(256), 0, stream>>>(x, wt, bq, bk, bv, qb, kb, vt);
    k_attn<<<dim3(GRIDX, BQ), dim3(256), 0, stream>>>(qb, kb, vt, cw, cb, out);
}

// Round 4
// 226.826 us; speedup vs baseline: 1.2215x; 1.2215x over previous
//
#include <hip/hip_runtime.h>
#include <hip/hip_bf16.h>

typedef __bf16 bf16_t;
typedef __bf16 bf16x8 __attribute__((ext_vector_type(8)));
typedef float  floatx4 __attribute__((ext_vector_type(4)));

#define BQ 16
#define NTOK 2048
#define DIM 256
#define HD 64

// ---------------- Kernel 0: W -> W^T bf16, + zero out-accumulator & rowsums ----------------
__global__ __launch_bounds__(256) void k_prep(const float* __restrict__ Wq,
                                              const float* __restrict__ Wk,
                                              const float* __restrict__ Wv,
                                              bf16_t* __restrict__ wt,
                                              float* __restrict__ outz,
                                              float* __restrict__ rsz) {
    int o = blockIdx.x * 256 + threadIdx.x;   // grid 1024 -> o < 262144
    if (o < 49152) {
        int w = o >> 14;
        int r = o & 16383;
        int h = r >> 8;
        int d = r & 255;
        const float* W = (w == 0) ? Wq : ((w == 1) ? Wk : Wv);
        wt[o] = (bf16_t)W[d * 64 + h];
    }
    // zero out (524288 float4) + rs (8192 float4)
    float4 z = make_float4(0.f, 0.f, 0.f, 0.f);
    for (int u = o; u < 532480; u += 262144) {
        if (u < 524288) ((float4*)outz)[u] = z;
        else            ((float4*)rsz)[u - 524288] = z;
    }
}

// ---------------- Kernel 1: QKV projection (64 tokens/block, 512 blocks) ----------------
#define XS 264
__global__ __launch_bounds__(256) void k_qkv(const float* __restrict__ x,
                                             const bf16_t* __restrict__ wt,
                                             const float* __restrict__ bq,
                                             const float* __restrict__ bk,
                                             const float* __restrict__ bv,
                                             bf16_t* __restrict__ qb,
                                             bf16_t* __restrict__ kb,
                                             bf16_t* __restrict__ vt) {
    __shared__ bf16_t x_ls[64 * XS];
    __shared__ bf16_t vt_ls[64 * 72];

    int b  = blockIdx.x >> 5;
    int t0 = (blockIdx.x & 31) << 6;
    int t  = threadIdx.x;
    int lane = t & 63;
    int w    = t >> 6;
    int m_   = lane & 15;
    int q4   = lane >> 4;

    for (int tau = t; tau < 4096; tau += 256) {
        int row = tau >> 6, ch = tau & 63;
        float4 v = ((const float4*)x)[(size_t)(b * NTOK + t0 + row) * 64 + ch];
        bf16_t tmp[4] = {(bf16_t)v.x, (bf16_t)v.y, (bf16_t)v.z, (bf16_t)v.w};
        *(uint2*)(&x_ls[row * XS + ch * 4]) = *(uint2*)tmp;
    }
    __syncthreads();

    for (int wi = 0; wi < 3; ++wi) {
        const bf16_t* wtw = wt + wi * 16384;
        floatx4 acc[4];
        #pragma unroll
        for (int mt = 0; mt < 4; ++mt) acc[mt] = floatx4{0.f, 0.f, 0.f, 0.f};

        #pragma unroll
        for (int ks = 0; ks < 8; ++ks) {
            bf16x8 bfrag = *(const bf16x8*)(wtw + (16 * w + m_) * 256 + ks * 32 + q4 * 8);
            #pragma unroll
            for (int mt = 0; mt < 4; ++mt) {
                bf16x8 afrag = *(const bf16x8*)(&x_ls[(16 * mt + m_) * XS + ks * 32 + q4 * 8]);
                acc[mt] = __builtin_amdgcn_mfma_f32_16x16x32_bf16(afrag, bfrag, acc[mt], 0, 0, 0);
            }
        }
        const float* bias_p = (wi == 0) ? bq : ((wi == 1) ? bk : bv);
        float bias = bias_p[16 * w + m_];
        float scale = (wi == 0) ? 0.125f : 1.0f;   // fold H^-0.5 into q (exact pow2)

        if (wi < 2) {
            bf16_t* dst = (wi == 0) ? qb : kb;
            #pragma unroll
            for (int mt = 0; mt < 4; ++mt)
                #pragma unroll
                for (int r = 0; r < 4; ++r) {
                    int tok = t0 + 16 * mt + 4 * q4 + r;
                    dst[(size_t)(b * NTOK + tok) * 64 + 16 * w + m_] = (bf16_t)((acc[mt][r] + bias) * scale);
                }
        } else {
            #pragma unroll
            for (int mt = 0; mt < 4; ++mt)
                #pragma unroll
                for (int r = 0; r < 4; ++r)
                    vt_ls[(16 * w + m_) * 72 + 16 * mt + 4 * q4 + r] = (bf16_t)(acc[mt][r] + bias);
            __syncthreads();
            for (int tau = t; tau < 512; tau += 256) {
                int h = tau >> 3, ch = tau & 7;
                uint4 val = *(const uint4*)(&vt_ls[h * 72 + ch * 8]);
                *(uint4*)(vt + (size_t)(b * 64 + h) * NTOK + t0 + ch * 8) = val;
            }
        }
    }
}

// ---------------- Kernel 2: fused attention (col-split x3, atomic partials) ----------------
// frame: 48 rows (r0-1..r0+46, interior 46) x 48 cols per iter; 15 iters per chunk
#define SA 52     // A_ls fp32 stride (cols 48..51 zero pad)
#define SP 72     // bf16 LDS stride
#define RINT 46
#define NIT_C 15  // col iterations per chunk (3 chunks x 15 = 45)
__global__ __launch_bounds__(256) void k_attn(const bf16_t* __restrict__ qb,
                                              const bf16_t* __restrict__ kb,
                                              const bf16_t* __restrict__ vt,
                                              const float* __restrict__ conv_w,
                                              const float* __restrict__ conv_b,
                                              float* __restrict__ outp,
                                              float* __restrict__ rsg) {
    __shared__ bf16_t q_ls[48 * SP];
    __shared__ bf16_t k_ls[48 * SP];
    __shared__ bf16_t v_ls[64 * SP];   // [h][k], k=global_col-c0; k>=46 zero
    __shared__ float  A_ls[48 * SA];
    __shared__ bf16_t p_ls[48 * SP];   // [i][k]; rows 0,47 & k>=46 zero

    int b    = blockIdx.z;
    int r0   = blockIdx.x * RINT;
    int ch0  = blockIdx.y * NIT_C;     // first col-iter index of this chunk
    int t = threadIdx.x, lane = t & 63, w = t >> 6;
    int m_ = lane & 15, q4 = lane >> 4;

    const uint* vt32 = (const uint*)vt + (size_t)b * 64 * 1024;

    int vh[6], vc[6];
    #pragma unroll
    for (int j = 0; j < 6; ++j) { int tau = t + 256 * j; vh[j] = tau / 23; vc[j] = tau % 23; }

    float cw[9];
    #pragma unroll
    for (int i = 0; i < 9; ++i) cw[i] = conv_w[i];
    float cb = conv_b[0];

    uint4 kreg[2];
    uint  vreg[6];
    auto prefetch = [&](int c0) {
        {
            int row = t >> 3, ch = t & 7;
            int g = c0 - 1 + row;
            uint4 val = make_uint4(0u, 0u, 0u, 0u);
            if (g >= 0 && g < NTOK)
                val = *(const uint4*)(kb + (size_t)(b * NTOK + g) * 64 + ch * 8);
            kreg[0] = val;
        }
        if (t < 128) {
            int row = (t + 256) >> 3, ch = t & 7;
            int g = c0 - 1 + row;
            uint4 val = make_uint4(0u, 0u, 0u, 0u);
            if (g >= 0 && g < NTOK)
                val = *(const uint4*)(kb + (size_t)(b * NTOK + g) * 64 + ch * 8);
            kreg[1] = val;
        }
        #pragma unroll
        for (int j = 0; j < 6; ++j) {
            if (t + 256 * j < 1472) {
                int n = c0 + 2 * vc[j];
                uint val = 0u;
                if (n < NTOK) val = vt32[vh[j] * 1024 + (n >> 1)];
                vreg[j] = val;
            }
        }
    };

    prefetch(ch0 * RINT);

    // one-time zero inits
    for (int u = t; u < 1728; u += 256) ((uint*)p_ls)[u] = 0u;            // whole p_ls
    for (int u = t; u < 1152; u += 256) {                                  // v_ls K-pad cols 46..63
        int h = u / 18, c = 46 + u % 18;
        v_ls[h * SP + c] = (bf16_t)0.f;
    }
    if (t < 192) A_ls[(t >> 2) * SA + 48 + (t & 3)] = 0.f;                 // A_ls col pad
    // stage q (48 rows x 8 x 16B)
    for (int tau = t; tau < 384; tau += 256) {
        int row = tau >> 3, ch = tau & 7;
        int g = r0 - 1 + row;
        uint4 val = make_uint4(0u, 0u, 0u, 0u);
        if (g >= 0 && g < NTOK)
            val = *(const uint4*)(qb + (size_t)(b * NTOK + g) * 64 + ch * 8);
        *(uint4*)(&q_ls[row * SP + ch * 8]) = val;
    }

    floatx4 accO[3];
    #pragma unroll
    for (int ti = 0; ti < 3; ++ti) accO[ti] = floatx4{0.f, 0.f, 0.f, 0.f};
    float rs[3] = {0.f, 0.f, 0.f};

    for (int it = 0; it < NIT_C; ++it) {
        // ---- regs -> LDS (k_ls, v_ls) ----
        {
            int row = t >> 3, ch = t & 7;
            *(uint4*)(&k_ls[row * SP + ch * 8]) = kreg[0];
            if (t < 128) {
                int row1 = (t + 256) >> 3;
                *(uint4*)(&k_ls[row1 * SP + ch * 8]) = kreg[1];
            }
            #pragma unroll
            for (int j = 0; j < 6; ++j)
                if (t + 256 * j < 1472)
                    *(uint*)(&v_ls[vh[j] * SP + 2 * vc[j]]) = vreg[j];
        }
        __syncthreads();

        // ---- QK^T: 9 tiles, K=64 (scale pre-folded into q) ----
        for (int T = w; T < 9; T += 4) {
            int ti = T / 3, tj = T % 3;
            floatx4 a = floatx4{0.f, 0.f, 0.f, 0.f};
            #pragma unroll
            for (int ks = 0; ks < 2; ++ks) {
                bf16x8 af = *(const bf16x8*)(&q_ls[(16 * ti + m_) * SP + ks * 32 + q4 * 8]);
                bf16x8 bf = *(const bf16x8*)(&k_ls[(16 * tj + m_) * SP + ks * 32 + q4 * 8]);
                a = __builtin_amdgcn_mfma_f32_16x16x32_bf16(af, bf, a, 0, 0, 0);
            }
            #pragma unroll
            for (int r = 0; r < 4; ++r)
                A_ls[(16 * ti + 4 * q4 + r) * SA + 16 * tj + m_] = a[r];
        }
        __syncthreads();

        // issue next iter's global loads; latency overlaps conv below
        if (it + 1 < NIT_C) prefetch((ch0 + it + 1) * RINT);

        // ---- conv + sigmoid + relu + expm1 (1x4 quads, vector taps) ----
        #pragma unroll
        for (int round = 0; round < 3; ++round) {
            int idx = t + (round << 8);
            if (idx < 552) {
                int i = idx / 12 + 1;            // row 1..46
                int g = idx - (i - 1) * 12;      // quad col group 0..11
                const float* base = &A_ls[(i - 1) * SA + 4 * g];
                float a0[6], a1[6], a2[6];
                *(float4*)(a0) = *(const float4*)(base);
                *(float2*)(a0 + 4) = *(const float2*)(base + 4);
                *(float4*)(a1) = *(const float4*)(base + SA);
                *(float2*)(a1 + 4) = *(const float2*)(base + SA + 4);
                *(float4*)(a2) = *(const float4*)(base + 2 * SA);
                *(float2*)(a2 + 4) = *(const float2*)(base + 2 * SA + 4);
                float esum = 0.f;
                bf16_t quad[4];
                #pragma unroll
                for (int x = 0; x < 4; ++x) {
                    float conv = cb
                        + cw[0] * a0[x] + cw[1] * a0[x + 1] + cw[2] * a0[x + 2]
                        + cw[3] * a1[x] + cw[4] * a1[x + 1] + cw[5] * a1[x + 2]
                        + cw[6] * a2[x] + cw[7] * a2[x + 1] + cw[8] * a2[x + 2];
                    float sig = __builtin_amdgcn_rcpf(1.f + __expf(-conv));
                    float s = fmaxf(a1[x + 1] - sig, 0.f);
                    float ev = __expf(s) - 1.f;
                    if (4 * g + x > 45) ev = 0.f;     // frame col > 46 (rim / pad)
                    quad[x] = (bf16_t)ev;
                    esum += ev;
                }
                rs[round] += esum;
                *(uint2*)(&p_ls[i * SP + 4 * g]) = *(uint2*)quad;
            }
        }
        __syncthreads();

        // ---- PV: O[48x64] += P @ V ----
        #pragma unroll
        for (int ks = 0; ks < 2; ++ks) {
            bf16x8 bf = *(const bf16x8*)(&v_ls[(16 * w + m_) * SP + ks * 32 + q4 * 8]);
            #pragma unroll
            for (int ti = 0; ti < 3; ++ti) {
                bf16x8 af = *(const bf16x8*)(&p_ls[(16 * ti + m_) * SP + ks * 32 + q4 * 8]);
                accO[ti] = __builtin_amdgcn_mfma_f32_16x16x32_bf16(af, bf, accO[ti], 0, 0, 0);
            }
        }
        __syncthreads();
    }

    // ---- epilogue: partial rowsum reduce -> atomic; partial O -> atomic ----
    float* sc = A_ls;
    sc[t * 3 + 0] = rs[0];
    sc[t * 3 + 1] = rs[1];
    sc[t * 3 + 2] = rs[2];
    __syncthreads();
    if (t < RINT) {
        float s = 0.f;
        #pragma unroll
        for (int j = 0; j < 12; ++j) {
            int idx = 12 * t + j;
            s += sc[(idx & 255) * 3 + (idx >> 8)];
        }
        int grow = r0 + t;
        if (grow < NTOK) atomicAdd(&rsg[b * NTOK + grow], s);
    }

    #pragma unroll
    for (int ti = 0; ti < 3; ++ti) {
        #pragma unroll
        for (int r = 0; r < 4; ++r) {
            int i = 16 * ti + 4 * q4 + r;
            int grow = r0 + i - 1;
            if (i >= 1 && i < 47 && grow < NTOK)
                atomicAdd(&outp[((size_t)(b * NTOK + grow) << 6) + 16 * w + m_], accO[ti][r]);
        }
    }
}

// ---------------- Kernel 3: normalize out /= (rowsum + eps), in place ----------------
__global__ __launch_bounds__(256) void k_norm(float* __restrict__ out,
                                              const float* __restrict__ rsg) {
    int gid = blockIdx.x * 256 + threadIdx.x;   // 524288 float4s
    float4 o = ((float4*)out)[gid];
    float d = rsg[gid >> 4] + 1e-5f;
    float inv = 1.f / d;
    o.x *= inv; o.y *= inv; o.z *= inv; o.w *= inv;
    ((float4*)out)[gid] = o;
}

extern "C" void kernel_launch(void* const* d_in, const int* in_sizes, int n_in,
                              void* d_out, int out_size, void* d_ws, size_t ws_size,
                              hipStream_t stream) {
    const float* x  = (const float*)d_in[0];
    const float* Wq = (const float*)d_in[1];
    const float* bq = (const float*)d_in[2];
    const float* Wk = (const float*)d_in[3];
    const float* bk = (const float*)d_in[4];
    const float* Wv = (const float*)d_in[5];
    const float* bv = (const float*)d_in[6];
    const float* cw = (const float*)d_in[7];
    const float* cb = (const float*)d_in[8];
    float* out = (float*)d_out;

    char* ws = (char*)d_ws;
    bf16_t* wt = (bf16_t*)ws;                               // 98304 B
    bf16_t* qb = (bf16_t*)(ws + 98304);                     // 4 MB
    bf16_t* kb = (bf16_t*)(ws + 98304 + 4194304);           // 4 MB
    bf16_t* vt = (bf16_t*)(ws + 98304 + 8388608);           // 4 MB
    float*  rsg = (float*)(ws + 98304 + 12582912);          // 128 KB

    k_prep<<<dim3(1024), dim3(256), 0, stream>>>(Wq, Wk, Wv, wt, out, rsg);
    k_qkv<<<dim3(512), dim3(256), 0, stream>>>(x, wt, bq, bk, bv, qb, kb, vt);
    k_attn<<<dim3(45, 3, BQ), dim3(256), 0, stream>>>(qb, kb, vt, cw, cb, out, rsg);
    k_norm<<<dim3(2048), dim3(256), 0, stream>>>(out, rsg);
}